// Round 1
// baseline (817.727 us; speedup 1.0000x reference)
//
#include <hip/hip_runtime.h>
#include <math.h>

#define BB 4
#define TT 2048
#define VV 1024
#define CC 256
#define MR (BB*TT)   // 8192 rows

using short8 = __attribute__((ext_vector_type(8))) short;
using f32x4  = __attribute__((ext_vector_type(4))) float;

__device__ __forceinline__ float bs2f(unsigned short s) {
    return __uint_as_float(((unsigned int)s) << 16);
}
__device__ __forceinline__ unsigned short f2bs(float f) {
    unsigned int u = __float_as_uint(f);
    u += 0x7fffu + ((u >> 16) & 1u);          // round-to-nearest-even
    return (unsigned short)(u >> 16);
}

// ---------------------------------------------------------------------------
// Weight prep: WT[c][v] = softmax_v(basis[v]·coef[c]) as bf16 (B^T layout)
// grid = 256 (one block per column c), block = 256
__global__ void prep_softmax_w(const float* __restrict__ basis,
                               const float* __restrict__ coef, int nb2,
                               unsigned short* __restrict__ WT) {
    int c = blockIdx.x, t = threadIdx.x;
    __shared__ float red[256];
    __shared__ float cf[128];
    for (int j = t; j < nb2; j += 256) cf[j] = coef[c * nb2 + j];
    __syncthreads();
    float vals[4];
    #pragma unroll
    for (int i = 0; i < 4; ++i) {
        int v = t + i * 256;
        const float* br = basis + (size_t)v * nb2;
        float s = 0.f;
        for (int j = 0; j < nb2; ++j) s += br[j] * cf[j];
        vals[i] = s;
    }
    float m = fmaxf(fmaxf(vals[0], vals[1]), fmaxf(vals[2], vals[3]));
    red[t] = m; __syncthreads();
    for (int o = 128; o > 0; o >>= 1) { if (t < o) red[t] = fmaxf(red[t], red[t + o]); __syncthreads(); }
    float mx = red[0]; __syncthreads();
    float e[4], s = 0.f;
    #pragma unroll
    for (int i = 0; i < 4; ++i) { e[i] = expf(vals[i] - mx); s += e[i]; }
    red[t] = s; __syncthreads();
    for (int o = 128; o > 0; o >>= 1) { if (t < o) red[t] += red[t + o]; __syncthreads(); }
    float inv = 1.f / red[0];
    #pragma unroll
    for (int i = 0; i < 4; ++i) WT[(size_t)c * VV + t + i * 256] = f2bs(e[i] * inv);
}

// out[v][coloff+c] = (basis[v]·coef[c]) * s1[0]*s2[0]   (natural layout, bf16)
// grid = V*C/256, block = 256  (threads of a block share row v)
__global__ void prep_plain_w(const float* __restrict__ basis,
                             const float* __restrict__ coef, int nb2,
                             const float* s1, const float* s2,
                             unsigned short* __restrict__ out, int ldo, int coloff) {
    int idx = blockIdx.x * 256 + threadIdx.x;
    int v = idx >> 8, c = idx & 255;
    const float* br = basis + (size_t)v * nb2;
    const float* cr = coef + (size_t)c * nb2;
    float s = 0.f;
    for (int j = 0; j < nb2; ++j) s += br[j] * cr[j];
    out[(size_t)v * ldo + coloff + c] = f2bs(s * s1[0] * s2[0]);
}

// WT[n][k] = W[k][n], 256x256 fp32 -> bf16.  grid = 256, block = 256
__global__ void prep_T(const float* __restrict__ W, unsigned short* __restrict__ WT) {
    int n = blockIdx.x, k = threadIdx.x;
    WT[(size_t)n * 256 + k] = f2bs(W[(size_t)k * 256 + n]);
}

// ---------------------------------------------------------------------------
// RMS norm: one block per row (V=1024), bf16 out
__global__ void rmsnorm_k(const float* __restrict__ x, unsigned short* __restrict__ xn) {
    int row = blockIdx.x, t = threadIdx.x;
    const float4 v = reinterpret_cast<const float4*>(x + (size_t)row * VV)[t];
    __shared__ float red[256];
    red[t] = v.x * v.x + v.y * v.y + v.z * v.z + v.w * v.w;
    __syncthreads();
    for (int o = 128; o > 0; o >>= 1) { if (t < o) red[t] += red[t + o]; __syncthreads(); }
    float r = rsqrtf(red[0] * (1.f / VV) + 1.1920929e-7f);
    ushort4 u;
    u.x = f2bs(v.x * r); u.y = f2bs(v.y * r); u.z = f2bs(v.z * r); u.w = f2bs(v.w * r);
    reinterpret_cast<ushort4*>(xn + (size_t)row * VV)[t] = u;
}

// ---------------------------------------------------------------------------
// bf16 transpose per batch: (T,C) slice of qkv -> (C,T)
// grid (T/32, C/32, B), block 256 (32x8)
__global__ void transpose_TC(const unsigned short* __restrict__ src, int ldsrc,
                             unsigned short* __restrict__ dst) {
    __shared__ unsigned short tile[32][33];
    int b = blockIdx.z, t0 = blockIdx.x * 32, c0 = blockIdx.y * 32;
    int tx = threadIdx.x & 31, ty = threadIdx.x >> 5;
    #pragma unroll
    for (int i = 0; i < 4; ++i) {
        int r = ty + i * 8;
        tile[r][tx] = src[(size_t)(b * TT + t0 + r) * ldsrc + c0 + tx];
    }
    __syncthreads();
    #pragma unroll
    for (int i = 0; i < 4; ++i) {
        int r = ty + i * 8;
        dst[((size_t)b * CC + c0 + r) * TT + t0 + tx] = tile[tx][r];
    }
}

// ---------------------------------------------------------------------------
// GEMM: C[m,n] = sum_k A[m,k] * Bt[n,k]  (A,Bt bf16 row-major), 64x64 tile,
// 4 waves (2x2), mfma_f32_16x16x32_bf16. XOR-swizzled LDS (2-way = free).
struct EpiP {
    float* outf; const float* addf;
    unsigned short* outb; int ldo; int coloff;
    const float* bias;
    const unsigned short* aux; int ldaux;
};

template<int EPI>
__global__ __launch_bounds__(256)
void gemm_bt_k(const unsigned short* A, int lda,
               const unsigned short* Bt, int K, EpiP ep) {
    __shared__ short8 As[256], Bs[256];            // 64 rows x 4 chunks each
    const int tid = threadIdx.x;
    const int lane = tid & 63, wid = tid >> 6;
    const int wm = wid >> 1, wn = wid & 1;
    const int m0 = blockIdx.y * 64, n0 = blockIdx.x * 64;
    const int lrow = tid >> 2, lch = tid & 3;
    const int sws = lch ^ ((lrow >> 1) & 3);
    const unsigned short* ag = A + (size_t)(m0 + lrow) * lda + lch * 8;
    const unsigned short* bg = Bt + (size_t)(n0 + lrow) * K + lch * 8;

    f32x4 acc[2][2];
    #pragma unroll
    for (int i = 0; i < 2; ++i)
        #pragma unroll
        for (int j = 0; j < 2; ++j) acc[i][j] = {0.f, 0.f, 0.f, 0.f};

    const int g = lane >> 4;
    const int ra0 = wm * 32 + (lane & 15);
    const int rb0 = wn * 32 + (lane & 15);

    for (int k0 = 0; k0 < K; k0 += 32) {
        As[lrow * 4 + sws] = *reinterpret_cast<const short8*>(ag + k0);
        Bs[lrow * 4 + sws] = *reinterpret_cast<const short8*>(bg + k0);
        __syncthreads();
        short8 af[2], bf[2];
        #pragma unroll
        for (int i = 0; i < 2; ++i) {
            int ra = ra0 + i * 16;
            af[i] = As[ra * 4 + (g ^ ((ra >> 1) & 3))];
            int rb = rb0 + i * 16;
            bf[i] = Bs[rb * 4 + (g ^ ((rb >> 1) & 3))];
        }
        #pragma unroll
        for (int i = 0; i < 2; ++i)
            #pragma unroll
            for (int j = 0; j < 2; ++j)
                acc[i][j] = __builtin_amdgcn_mfma_f32_16x16x32_bf16(af[i], bf[j], acc[i][j], 0, 0, 0);
        __syncthreads();
    }

    #pragma unroll
    for (int i = 0; i < 2; ++i) {
        #pragma unroll
        for (int j = 0; j < 2; ++j) {
            #pragma unroll
            for (int r = 0; r < 4; ++r) {
                int m = m0 + wm * 32 + i * 16 + (lane >> 4) * 4 + r;
                int n = n0 + wn * 32 + j * 16 + (lane & 15);
                float v = acc[i][j][r];
                if constexpr (EPI == 0) {                       // plain bf16 store
                    ep.outb[(size_t)m * ep.ldo + ep.coloff + n] = f2bs(v);
                } else if constexpr (EPI == 1) {                // sigmoid(acc+bias)*aux
                    float s = 1.f / (1.f + expf(-(v + ep.bias[n])));
                    float a = bs2f(ep.aux[(size_t)m * ep.ldaux + n]);
                    ep.outb[(size_t)m * ep.ldo + ep.coloff + n] = f2bs(s * a);
                } else if constexpr (EPI == 2) {                // exact gelu(acc+bias)
                    float z = v + ep.bias[n];
                    float h = 0.5f * z * (1.f + erff(z * 0.70710678118654752f));
                    ep.outb[(size_t)m * ep.ldo + ep.coloff + n] = f2bs(h);
                } else {                                        // outf = addf + acc
                    size_t idx = (size_t)m * ep.ldo + n;
                    ep.outf[idx] = ep.addf[idx] + v;
                }
            }
        }
    }
}

// ---------------------------------------------------------------------------
// Decay-weighted retrieval: r[t,:] = sum_{s>t} (q_t·k_s) decay^(s-t-1) v_s
// One wave per 16 t-rows. s-tiles of 32; windowed scan (win bounds error<1e-8).
__global__ __launch_bounds__(64)
void attn_k(const unsigned short* __restrict__ qkv, int qoff, int koff,
            const unsigned short* __restrict__ vt,
            const float* __restrict__ dlogit,
            unsigned short* __restrict__ rout, int ldr, int win) {
    int blk = blockIdx.x;
    int b = blk >> 7;               // 128 t-tiles per batch
    int t0 = (blk & 127) << 4;
    int lane = threadIdx.x;
    float dec = 1.f / (1.f + expf(-dlogit[0]));
    float l2d = log2f(dec);

    short8 qf[8];
    const size_t rowq = (size_t)(b * TT + t0 + (lane & 15)) * 1536 + qoff + (lane >> 4) * 8;
    #pragma unroll
    for (int ch = 0; ch < 8; ++ch)
        qf[ch] = *reinterpret_cast<const short8*>(qkv + rowq + ch * 32);

    f32x4 racc[16];
    #pragma unroll
    for (int i = 0; i < 16; ++i) racc[i] = {0.f, 0.f, 0.f, 0.f};

    __shared__ short8 Pl[64];       // 16 rows x 4 swizzled chunks (bf16 16x32)
    unsigned short* pb = reinterpret_cast<unsigned short*>(Pl);

    int sBeg = t0 & ~31;
    int sEnd = TT;
    if (win > 0) { int e = (t0 + 16 + win + 31) & ~31; sEnd = e < TT ? e : TT; }
    const int tl = (lane >> 4) * 4;

    for (int s0 = sBeg; s0 < sEnd; s0 += 32) {
        #pragma unroll
        for (int h = 0; h < 2; ++h) {
            f32x4 sacc = {0.f, 0.f, 0.f, 0.f};
            const unsigned short* kb =
                qkv + (size_t)(b * TT + s0 + h * 16 + (lane & 15)) * 1536 + koff + (lane >> 4) * 8;
            #pragma unroll
            for (int ch = 0; ch < 8; ++ch) {
                short8 kf = *reinterpret_cast<const short8*>(kb + ch * 32);
                sacc = __builtin_amdgcn_mfma_f32_16x16x32_bf16(qf[ch], kf, sacc, 0, 0, 0);
            }
            int scol = s0 + h * 16 + (lane & 15);
            #pragma unroll
            for (int r = 0; r < 4; ++r) {
                int trow = t0 + tl + r;
                int d = scol - trow;
                float w = (d > 0) ? exp2f(l2d * (float)(d - 1)) : 0.f;
                int prow = tl + r, pcol = h * 16 + (lane & 15);
                int sw = (pcol >> 3) ^ ((prow >> 1) & 3);
                pb[(prow * 4 + sw) * 8 + (pcol & 7)] = f2bs(sacc[r] * w);
            }
        }
        __syncthreads();
        short8 pf;
        { int prow = lane & 15; pf = Pl[prow * 4 + ((lane >> 4) ^ ((prow >> 1) & 3))]; }
        __syncthreads();
        const unsigned short* vb = vt + ((size_t)b * CC + (lane & 15)) * TT + s0 + (lane >> 4) * 8;
        #pragma unroll
        for (int nt = 0; nt < 16; ++nt) {
            short8 vf = *reinterpret_cast<const short8*>(vb + (size_t)nt * 16 * TT);
            racc[nt] = __builtin_amdgcn_mfma_f32_16x16x32_bf16(pf, vf, racc[nt], 0, 0, 0);
        }
    }

    #pragma unroll
    for (int nt = 0; nt < 16; ++nt)
        #pragma unroll
        for (int r = 0; r < 4; ++r) {
            int trow = t0 + tl + r;
            int n = nt * 16 + (lane & 15);
            rout[(size_t)(b * TT + trow) * ldr + n] = f2bs(racc[nt][r]);
        }
}

// ---------------------------------------------------------------------------
extern "C" void kernel_launch(void* const* d_in, const int* in_sizes, int n_in,
                              void* d_out, int out_size, void* d_ws, size_t ws_size,
                              hipStream_t stream) {
    (void)in_sizes; (void)n_in; (void)out_size; (void)ws_size;
    const float* x          = (const float*)d_in[0];
    const float* basis_low  = (const float*)d_in[1];
    const float* basis_mid  = (const float*)d_in[2];
    const float* basis_high = (const float*)d_in[3];
    const float* slow_q = (const float*)d_in[4];
    const float* slow_k = (const float*)d_in[5];
    const float* slow_v = (const float*)d_in[6];
    const float* slow_o = (const float*)d_in[7];
    const float* slow_decay = (const float*)d_in[8];
    const float* slow_scale = (const float*)d_in[9];
    const float* fast_q = (const float*)d_in[10];
    const float* fast_k = (const float*)d_in[11];
    const float* fast_v = (const float*)d_in[12];
    const float* fast_o = (const float*)d_in[13];
    const float* fast_decay = (const float*)d_in[14];
    const float* fast_scale = (const float*)d_in[15];
    const float* low_read  = (const float*)d_in[16];
    const float* low_write = (const float*)d_in[17];
    const float* low_mix   = (const float*)d_in[18];
    const float* low_bias  = (const float*)d_in[19];
    const float* low_oscale= (const float*)d_in[20];
    const float* mid_read  = (const float*)d_in[21];
    const float* mid_write = (const float*)d_in[22];
    const float* mid_mix   = (const float*)d_in[23];
    const float* mid_bias  = (const float*)d_in[24];
    const float* mid_oscale= (const float*)d_in[25];
    const float* high_read  = (const float*)d_in[26];
    const float* high_write = (const float*)d_in[27];
    const float* high_mix   = (const float*)d_in[28];
    const float* high_bias  = (const float*)d_in[29];
    const float* high_oscale= (const float*)d_in[30];
    const float* tg_w    = (const float*)d_in[31];
    const float* tg_b    = (const float*)d_in[32];
    const float* alpha_w = (const float*)d_in[33];
    const float* alpha_b = (const float*)d_in[34];
    const float* mem_slow_scale = (const float*)d_in[35];
    const float* mem_fast_scale = (const float*)d_in[36];
    const float* op_low_scale   = (const float*)d_in[37];
    const float* op_mid_scale   = (const float*)d_in[38];
    const float* op_high_scale  = (const float*)d_in[39];
    float* out = (float*)d_out;

    char* ws = (char*)d_ws;
    size_t off = 0;
    auto alloc = [&](size_t n) { char* p = ws + off; off += (n + 255) & ~(size_t)255; return p; };
    unsigned short* WT_p1   = (unsigned short*)alloc((size_t)6 * CC * VV * 2);   // [1536][1024]
    unsigned short* Wcat_o  = (unsigned short*)alloc((size_t)VV * 512 * 2);      // [1024][512]
    unsigned short* WT_read = (unsigned short*)alloc((size_t)3 * CC * VV * 2);   // [768][1024]
    unsigned short* Wcat_w  = (unsigned short*)alloc((size_t)VV * 768 * 2);      // [1024][768]
    unsigned short* WT_mix  = (unsigned short*)alloc((size_t)3 * 65536 * 2);
    unsigned short* WT_tg   = (unsigned short*)alloc((size_t)65536 * 2);
    unsigned short* WT_al   = (unsigned short*)alloc((size_t)65536 * 2);
    unsigned short* xn      = (unsigned short*)alloc((size_t)MR * VV * 2);       // reused ph2
    unsigned short* qkv     = (unsigned short*)alloc((size_t)MR * 1536 * 2);
    unsigned short* vt_s    = (unsigned short*)alloc((size_t)BB * CC * TT * 2);
    unsigned short* vt_f    = (unsigned short*)alloc((size_t)BB * CC * TT * 2);
    unsigned short* rcat    = (unsigned short*)alloc((size_t)MR * 512 * 2);
    unsigned short* rfast   = (unsigned short*)alloc((size_t)MR * CC * 2);
    unsigned short* hhigh   = (unsigned short*)alloc((size_t)MR * CC * 2);
    // z and hcat overlay the (dead-by-then) qkv region
    unsigned short* z    = qkv;
    unsigned short* hcat = qkv + (size_t)MR * 768;

    // ---- weight prep ----
    prep_softmax_w<<<256, 256, 0, stream>>>(basis_low,  slow_q, 32,  WT_p1 + (size_t)0 * CC * VV);
    prep_softmax_w<<<256, 256, 0, stream>>>(basis_low,  slow_k, 32,  WT_p1 + (size_t)1 * CC * VV);
    prep_softmax_w<<<256, 256, 0, stream>>>(basis_low,  slow_v, 32,  WT_p1 + (size_t)2 * CC * VV);
    prep_softmax_w<<<256, 256, 0, stream>>>(basis_high, fast_q, 128, WT_p1 + (size_t)3 * CC * VV);
    prep_softmax_w<<<256, 256, 0, stream>>>(basis_high, fast_k, 128, WT_p1 + (size_t)4 * CC * VV);
    prep_softmax_w<<<256, 256, 0, stream>>>(basis_high, fast_v, 128, WT_p1 + (size_t)5 * CC * VV);
    prep_softmax_w<<<256, 256, 0, stream>>>(basis_low,  low_read,  32,  WT_read + (size_t)0 * CC * VV);
    prep_softmax_w<<<256, 256, 0, stream>>>(basis_mid,  mid_read,  64,  WT_read + (size_t)1 * CC * VV);
    prep_softmax_w<<<256, 256, 0, stream>>>(basis_high, high_read, 128, WT_read + (size_t)2 * CC * VV);
    prep_plain_w<<<1024, 256, 0, stream>>>(basis_low,  slow_o, 32,  slow_scale, mem_slow_scale, Wcat_o, 512, 0);
    prep_plain_w<<<1024, 256, 0, stream>>>(basis_high, fast_o, 128, fast_scale, mem_fast_scale, Wcat_o, 512, 256);
    prep_plain_w<<<1024, 256, 0, stream>>>(basis_low,  low_write,  32,  low_oscale,  op_low_scale,  Wcat_w, 768, 0);
    prep_plain_w<<<1024, 256, 0, stream>>>(basis_mid,  mid_write,  64,  mid_oscale,  op_mid_scale,  Wcat_w, 768, 256);
    prep_plain_w<<<1024, 256, 0, stream>>>(basis_high, high_write, 128, high_oscale, op_high_scale, Wcat_w, 768, 512);
    prep_T<<<256, 256, 0, stream>>>(tg_w, WT_tg);
    prep_T<<<256, 256, 0, stream>>>(alpha_w, WT_al);
    prep_T<<<256, 256, 0, stream>>>(low_mix,  WT_mix + 0 * 65536);
    prep_T<<<256, 256, 0, stream>>>(mid_mix,  WT_mix + 1 * 65536);
    prep_T<<<256, 256, 0, stream>>>(high_mix, WT_mix + 2 * 65536);

    // ---- phase 1 ----
    rmsnorm_k<<<MR, 256, 0, stream>>>(x, xn);
    { EpiP ep{}; ep.outb = qkv; ep.ldo = 1536; ep.coloff = 0;
      gemm_bt_k<0><<<dim3(24, 128), 256, 0, stream>>>(xn, 1024, WT_p1, 1024, ep); }
    transpose_TC<<<dim3(64, 8, 4), 256, 0, stream>>>(qkv + 512, 1536, vt_s);
    transpose_TC<<<dim3(64, 8, 4), 256, 0, stream>>>(qkv + 1280, 1536, vt_f);
    attn_k<<<512, 64, 0, stream>>>(qkv, 0,   256,  vt_s, slow_decay, rcat, 512, 768);
    attn_k<<<512, 64, 0, stream>>>(qkv, 768, 1024, vt_f, fast_decay, rfast, 256, 288);
    { EpiP ep{}; ep.outb = rcat; ep.ldo = 512; ep.coloff = 256;
      ep.bias = tg_b; ep.aux = rfast; ep.ldaux = 256;
      gemm_bt_k<1><<<dim3(4, 128), 256, 0, stream>>>(rcat, 512, WT_tg, 256, ep); }
    { EpiP ep{}; ep.outf = out; ep.addf = x; ep.ldo = 1024;
      gemm_bt_k<3><<<dim3(16, 128), 256, 0, stream>>>(rcat, 512, Wcat_o, 512, ep); }

    // ---- phase 2 ----
    rmsnorm_k<<<MR, 256, 0, stream>>>(out, xn);
    { EpiP ep{}; ep.outb = z; ep.ldo = 768; ep.coloff = 0;
      gemm_bt_k<0><<<dim3(12, 128), 256, 0, stream>>>(xn, 1024, WT_read, 1024, ep); }
    { EpiP ep{}; ep.outb = hcat; ep.ldo = 768; ep.coloff = 0; ep.bias = low_bias;
      gemm_bt_k<2><<<dim3(4, 128), 256, 0, stream>>>(z + 0, 768, WT_mix + 0 * 65536, 256, ep); }
    { EpiP ep{}; ep.outb = hcat; ep.ldo = 768; ep.coloff = 256; ep.bias = mid_bias;
      gemm_bt_k<2><<<dim3(4, 128), 256, 0, stream>>>(z + 256, 768, WT_mix + 1 * 65536, 256, ep); }
    { EpiP ep{}; ep.outb = hhigh; ep.ldo = 256; ep.coloff = 0; ep.bias = high_bias;
      gemm_bt_k<2><<<dim3(4, 128), 256, 0, stream>>>(z + 512, 768, WT_mix + 2 * 65536, 256, ep); }
    { EpiP ep{}; ep.outb = hcat; ep.ldo = 768; ep.coloff = 512;
      ep.bias = alpha_b; ep.aux = hhigh; ep.ldaux = 256;
      gemm_bt_k<1><<<dim3(4, 128), 256, 0, stream>>>(hcat, 768, WT_al, 256, ep); }
    { EpiP ep{}; ep.outf = out; ep.addf = out; ep.ldo = 1024;
      gemm_bt_k<3><<<dim3(16, 128), 256, 0, stream>>>(hcat, 768, Wcat_w, 768, ep); }
}

// Round 2
// 630.201 us; speedup vs baseline: 1.2976x; 1.2976x over previous
//
#include <hip/hip_runtime.h>
#include <math.h>

#define BB 4
#define TT 2048
#define VV 1024
#define CC 256
#define MR (BB*TT)   // 8192 rows

using short8  = __attribute__((ext_vector_type(8))) short;
using ushort8 = __attribute__((ext_vector_type(8))) unsigned short;
using f32x4   = __attribute__((ext_vector_type(4))) float;

__device__ __forceinline__ float bs2f(unsigned short s) {
    return __uint_as_float(((unsigned int)s) << 16);
}
__device__ __forceinline__ unsigned short f2bs(float f) {
    unsigned int u = __float_as_uint(f);
    u += 0x7fffu + ((u >> 16) & 1u);          // round-to-nearest-even
    return (unsigned short)(u >> 16);
}

// ---------------------------------------------------------------------------
// Weight prep: WT[c][v] = softmax_v(basis[v]·coef[c]) as bf16 (B^T layout)
// grid = 256 (one block per column c), block = 256
__global__ void prep_softmax_w(const float* __restrict__ basis,
                               const float* __restrict__ coef, int nb2,
                               unsigned short* __restrict__ WT) {
    int c = blockIdx.x, t = threadIdx.x;
    __shared__ float red[256];
    __shared__ float cf[128];
    for (int j = t; j < nb2; j += 256) cf[j] = coef[c * nb2 + j];
    __syncthreads();
    float vals[4];
    #pragma unroll
    for (int i = 0; i < 4; ++i) {
        int v = t + i * 256;
        const float* br = basis + (size_t)v * nb2;
        float s = 0.f;
        for (int j = 0; j < nb2; ++j) s += br[j] * cf[j];
        vals[i] = s;
    }
    float m = fmaxf(fmaxf(vals[0], vals[1]), fmaxf(vals[2], vals[3]));
    red[t] = m; __syncthreads();
    for (int o = 128; o > 0; o >>= 1) { if (t < o) red[t] = fmaxf(red[t], red[t + o]); __syncthreads(); }
    float mx = red[0]; __syncthreads();
    float e[4], s = 0.f;
    #pragma unroll
    for (int i = 0; i < 4; ++i) { e[i] = expf(vals[i] - mx); s += e[i]; }
    red[t] = s; __syncthreads();
    for (int o = 128; o > 0; o >>= 1) { if (t < o) red[t] += red[t + o]; __syncthreads(); }
    float inv = 1.f / red[0];
    #pragma unroll
    for (int i = 0; i < 4; ++i) WT[(size_t)c * VV + t + i * 256] = f2bs(e[i] * inv);
}

// out[v][coloff+c] = (basis[v]·coef[c]) * s1[0]*s2[0]   (natural layout, bf16)
__global__ void prep_plain_w(const float* __restrict__ basis,
                             const float* __restrict__ coef, int nb2,
                             const float* s1, const float* s2,
                             unsigned short* __restrict__ out, int ldo, int coloff) {
    int idx = blockIdx.x * 256 + threadIdx.x;
    int v = idx >> 8, c = idx & 255;
    const float* br = basis + (size_t)v * nb2;
    const float* cr = coef + (size_t)c * nb2;
    float s = 0.f;
    for (int j = 0; j < nb2; ++j) s += br[j] * cr[j];
    out[(size_t)v * ldo + coloff + c] = f2bs(s * s1[0] * s2[0]);
}

// WT[n][k] = W[k][n], 256x256 fp32 -> bf16.  grid = 256, block = 256
__global__ void prep_T(const float* __restrict__ W, unsigned short* __restrict__ WT) {
    int n = blockIdx.x, k = threadIdx.x;
    WT[(size_t)n * 256 + k] = f2bs(W[(size_t)k * 256 + n]);
}

// ---------------------------------------------------------------------------
// RMS norm: one block per row (V=1024), bf16 out
__global__ void rmsnorm_k(const float* __restrict__ x, unsigned short* __restrict__ xn) {
    int row = blockIdx.x, t = threadIdx.x;
    const float4 v = reinterpret_cast<const float4*>(x + (size_t)row * VV)[t];
    __shared__ float red[256];
    red[t] = v.x * v.x + v.y * v.y + v.z * v.z + v.w * v.w;
    __syncthreads();
    for (int o = 128; o > 0; o >>= 1) { if (t < o) red[t] += red[t + o]; __syncthreads(); }
    float r = rsqrtf(red[0] * (1.f / VV) + 1.1920929e-7f);
    ushort4 u;
    u.x = f2bs(v.x * r); u.y = f2bs(v.y * r); u.z = f2bs(v.z * r); u.w = f2bs(v.w * r);
    reinterpret_cast<ushort4*>(xn + (size_t)row * VV)[t] = u;
}

// ---------------------------------------------------------------------------
// bf16 transpose per batch: (T,C) slice of qkv -> (C,T)
__global__ void transpose_TC(const unsigned short* __restrict__ src, int ldsrc,
                             unsigned short* __restrict__ dst) {
    __shared__ unsigned short tile[32][33];
    int b = blockIdx.z, t0 = blockIdx.x * 32, c0 = blockIdx.y * 32;
    int tx = threadIdx.x & 31, ty = threadIdx.x >> 5;
    #pragma unroll
    for (int i = 0; i < 4; ++i) {
        int r = ty + i * 8;
        tile[r][tx] = src[(size_t)(b * TT + t0 + r) * ldsrc + c0 + tx];
    }
    __syncthreads();
    #pragma unroll
    for (int i = 0; i < 4; ++i) {
        int r = ty + i * 8;
        dst[((size_t)b * CC + c0 + r) * TT + t0 + tx] = tile[tx][r];
    }
}

// ---------------------------------------------------------------------------
// GEMM: C[m,n] = sum_k A[m,k] * Bt[n,k]  (A,Bt bf16 row-major), 64x64 tile,
// 4 waves (2x2), mfma_f32_16x16x32_bf16. XOR-swizzled LDS (2-way = free).
struct EpiP {
    float* outf; const float* addf;
    unsigned short* outb; int ldo; int coloff;
    const float* bias;
    const unsigned short* aux; int ldaux;
};

template<int EPI>
__global__ __launch_bounds__(256)
void gemm_bt_k(const unsigned short* A, int lda,
               const unsigned short* Bt, int K, EpiP ep) {
    __shared__ short8 As[256], Bs[256];            // 64 rows x 4 chunks each
    const int tid = threadIdx.x;
    const int lane = tid & 63, wid = tid >> 6;
    const int wm = wid >> 1, wn = wid & 1;
    const int m0 = blockIdx.y * 64, n0 = blockIdx.x * 64;
    const int lrow = tid >> 2, lch = tid & 3;
    const int sws = lch ^ ((lrow >> 1) & 3);
    const unsigned short* ag = A + (size_t)(m0 + lrow) * lda + lch * 8;
    const unsigned short* bg = Bt + (size_t)(n0 + lrow) * K + lch * 8;

    f32x4 acc[2][2];
    #pragma unroll
    for (int i = 0; i < 2; ++i)
        #pragma unroll
        for (int j = 0; j < 2; ++j) acc[i][j] = {0.f, 0.f, 0.f, 0.f};

    const int g = lane >> 4;
    const int ra0 = wm * 32 + (lane & 15);
    const int rb0 = wn * 32 + (lane & 15);

    for (int k0 = 0; k0 < K; k0 += 32) {
        As[lrow * 4 + sws] = *reinterpret_cast<const short8*>(ag + k0);
        Bs[lrow * 4 + sws] = *reinterpret_cast<const short8*>(bg + k0);
        __syncthreads();
        short8 af[2], bf[2];
        #pragma unroll
        for (int i = 0; i < 2; ++i) {
            int ra = ra0 + i * 16;
            af[i] = As[ra * 4 + (g ^ ((ra >> 1) & 3))];
            int rb = rb0 + i * 16;
            bf[i] = Bs[rb * 4 + (g ^ ((rb >> 1) & 3))];
        }
        #pragma unroll
        for (int i = 0; i < 2; ++i)
            #pragma unroll
            for (int j = 0; j < 2; ++j)
                acc[i][j] = __builtin_amdgcn_mfma_f32_16x16x32_bf16(af[i], bf[j], acc[i][j], 0, 0, 0);
        __syncthreads();
    }

    #pragma unroll
    for (int i = 0; i < 2; ++i) {
        #pragma unroll
        for (int j = 0; j < 2; ++j) {
            #pragma unroll
            for (int r = 0; r < 4; ++r) {
                int m = m0 + wm * 32 + i * 16 + (lane >> 4) * 4 + r;
                int n = n0 + wn * 32 + j * 16 + (lane & 15);
                float v = acc[i][j][r];
                if constexpr (EPI == 0) {                       // plain bf16 store
                    ep.outb[(size_t)m * ep.ldo + ep.coloff + n] = f2bs(v);
                } else if constexpr (EPI == 1) {                // sigmoid(acc+bias)*aux
                    float s = 1.f / (1.f + expf(-(v + ep.bias[n])));
                    float a = bs2f(ep.aux[(size_t)m * ep.ldaux + n]);
                    ep.outb[(size_t)m * ep.ldo + ep.coloff + n] = f2bs(s * a);
                } else if constexpr (EPI == 2) {                // exact gelu(acc+bias)
                    float z = v + ep.bias[n];
                    float h = 0.5f * z * (1.f + erff(z * 0.70710678118654752f));
                    ep.outb[(size_t)m * ep.ldo + ep.coloff + n] = f2bs(h);
                } else {                                        // outf = addf + acc
                    size_t idx = (size_t)m * ep.ldo + n;
                    ep.outf[idx] = ep.addf[idx] + v;
                }
            }
        }
    }
}

// ---------------------------------------------------------------------------
// Decay-weighted retrieval, 4 waves/block splitting the s-scan.
// Block = 256 threads; each block owns a 16-row t-tile; wave w takes s-tiles
// sBeg + (w + 4k)*32. Private P buffer per wave (intra-wave LDS ordering via
// lgkmcnt(0); per-wave LDS ops return in-order). Cross-wave fp32 reduction in
// LDS, then cooperative vectorized bf16 write-out.
__global__ __launch_bounds__(256)
void attn_k(const unsigned short* __restrict__ qkv, int qoff, int koff,
            const unsigned short* __restrict__ vt,
            const float* __restrict__ dlogit,
            unsigned short* __restrict__ rout, int ldr, int win) {
    int blk = blockIdx.x;
    int b = blk >> 7;               // 128 t-tiles per batch
    int t0 = (blk & 127) << 4;
    int tid = threadIdx.x;
    int lane = tid & 63, wid = tid >> 6;
    float dec = 1.f / (1.f + expf(-dlogit[0]));
    float l2d = log2f(dec);

    __shared__ short8 Pl[4][64];    // per-wave 16x32 bf16, swizzled chunks
    __shared__ float  red[16][260]; // LD=260 -> exactly 2-way bank alias (free)

    short8 qf[8];
    const size_t rowq = (size_t)(b * TT + t0 + (lane & 15)) * 1536 + qoff + (lane >> 4) * 8;
    #pragma unroll
    for (int ch = 0; ch < 8; ++ch)
        qf[ch] = *reinterpret_cast<const short8*>(qkv + rowq + ch * 32);

    f32x4 racc[16];
    #pragma unroll
    for (int i = 0; i < 16; ++i) racc[i] = {0.f, 0.f, 0.f, 0.f};

    unsigned short* pb = reinterpret_cast<unsigned short*>(&Pl[wid][0]);

    int sBeg = t0 & ~31;
    int sEnd = TT;
    if (win > 0) { int e = (t0 + 16 + win + 31) & ~31; sEnd = e < TT ? e : TT; }
    const int tl = (lane >> 4) * 4;

    for (int s0 = sBeg + wid * 32; s0 < sEnd; s0 += 128) {
        #pragma unroll
        for (int h = 0; h < 2; ++h) {
            f32x4 sacc = {0.f, 0.f, 0.f, 0.f};
            const unsigned short* kb =
                qkv + (size_t)(b * TT + s0 + h * 16 + (lane & 15)) * 1536 + koff + (lane >> 4) * 8;
            #pragma unroll
            for (int ch = 0; ch < 8; ++ch) {
                short8 kf = *reinterpret_cast<const short8*>(kb + ch * 32);
                sacc = __builtin_amdgcn_mfma_f32_16x16x32_bf16(qf[ch], kf, sacc, 0, 0, 0);
            }
            int scol = s0 + h * 16 + (lane & 15);
            #pragma unroll
            for (int r = 0; r < 4; ++r) {
                int trow = t0 + tl + r;
                int d = scol - trow;
                float w = (d > 0) ? exp2f(l2d * (float)(d - 1)) : 0.f;
                int prow = tl + r, pcol = h * 16 + (lane & 15);
                int sw = (pcol >> 3) ^ ((prow >> 1) & 3);
                pb[(prow * 4 + sw) * 8 + (pcol & 7)] = f2bs(sacc[r] * w);
            }
        }
        asm volatile("s_waitcnt lgkmcnt(0)" ::: "memory");
        __builtin_amdgcn_sched_barrier(0);
        short8 pf;
        { int prow = lane & 15; pf = Pl[wid][prow * 4 + ((lane >> 4) ^ ((prow >> 1) & 3))]; }
        const unsigned short* vb = vt + ((size_t)b * CC + (lane & 15)) * TT + s0 + (lane >> 4) * 8;
        #pragma unroll
        for (int nt = 0; nt < 16; ++nt) {
            short8 vf = *reinterpret_cast<const short8*>(vb + (size_t)nt * 16 * TT);
            racc[nt] = __builtin_amdgcn_mfma_f32_16x16x32_bf16(pf, vf, racc[nt], 0, 0, 0);
        }
    }

    // cross-wave reduction into red[][]
    for (int w = 0; w < 4; ++w) {
        if (wid == w) {
            #pragma unroll
            for (int nt = 0; nt < 16; ++nt)
                #pragma unroll
                for (int r = 0; r < 4; ++r) {
                    int row = tl + r, col = nt * 16 + (lane & 15);
                    if (w == 0) red[row][col] = racc[nt][r];
                    else        red[row][col] += racc[nt][r];
                }
        }
        __syncthreads();
    }

    // cooperative write-out: thread -> (row = tid>>4, 16 cols)
    {
        int row = tid >> 4, c0 = (tid & 15) * 16;
        ushort8 lo, hi;
        #pragma unroll
        for (int j = 0; j < 8; ++j) lo[j] = f2bs(red[row][c0 + j]);
        #pragma unroll
        for (int j = 0; j < 8; ++j) hi[j] = f2bs(red[row][c0 + 8 + j]);
        unsigned short* dst = rout + (size_t)(b * TT + t0 + row) * ldr + c0;
        *reinterpret_cast<ushort8*>(dst)     = lo;
        *reinterpret_cast<ushort8*>(dst + 8) = hi;
    }
}

// ---------------------------------------------------------------------------
extern "C" void kernel_launch(void* const* d_in, const int* in_sizes, int n_in,
                              void* d_out, int out_size, void* d_ws, size_t ws_size,
                              hipStream_t stream) {
    (void)in_sizes; (void)n_in; (void)out_size; (void)ws_size;
    const float* x          = (const float*)d_in[0];
    const float* basis_low  = (const float*)d_in[1];
    const float* basis_mid  = (const float*)d_in[2];
    const float* basis_high = (const float*)d_in[3];
    const float* slow_q = (const float*)d_in[4];
    const float* slow_k = (const float*)d_in[5];
    const float* slow_v = (const float*)d_in[6];
    const float* slow_o = (const float*)d_in[7];
    const float* slow_decay = (const float*)d_in[8];
    const float* slow_scale = (const float*)d_in[9];
    const float* fast_q = (const float*)d_in[10];
    const float* fast_k = (const float*)d_in[11];
    const float* fast_v = (const float*)d_in[12];
    const float* fast_o = (const float*)d_in[13];
    const float* fast_decay = (const float*)d_in[14];
    const float* fast_scale = (const float*)d_in[15];
    const float* low_read  = (const float*)d_in[16];
    const float* low_write = (const float*)d_in[17];
    const float* low_mix   = (const float*)d_in[18];
    const float* low_bias  = (const float*)d_in[19];
    const float* low_oscale= (const float*)d_in[20];
    const float* mid_read  = (const float*)d_in[21];
    const float* mid_write = (const float*)d_in[22];
    const float* mid_mix   = (const float*)d_in[23];
    const float* mid_bias  = (const float*)d_in[24];
    const float* mid_oscale= (const float*)d_in[25];
    const float* high_read  = (const float*)d_in[26];
    const float* high_write = (const float*)d_in[27];
    const float* high_mix   = (const float*)d_in[28];
    const float* high_bias  = (const float*)d_in[29];
    const float* high_oscale= (const float*)d_in[30];
    const float* tg_w    = (const float*)d_in[31];
    const float* tg_b    = (const float*)d_in[32];
    const float* alpha_w = (const float*)d_in[33];
    const float* alpha_b = (const float*)d_in[34];
    const float* mem_slow_scale = (const float*)d_in[35];
    const float* mem_fast_scale = (const float*)d_in[36];
    const float* op_low_scale   = (const float*)d_in[37];
    const float* op_mid_scale   = (const float*)d_in[38];
    const float* op_high_scale  = (const float*)d_in[39];
    float* out = (float*)d_out;

    char* ws = (char*)d_ws;
    size_t off = 0;
    auto alloc = [&](size_t n) { char* p = ws + off; off += (n + 255) & ~(size_t)255; return p; };
    unsigned short* WT_p1   = (unsigned short*)alloc((size_t)6 * CC * VV * 2);   // [1536][1024]
    unsigned short* Wcat_o  = (unsigned short*)alloc((size_t)VV * 512 * 2);      // [1024][512]
    unsigned short* WT_read = (unsigned short*)alloc((size_t)3 * CC * VV * 2);   // [768][1024]
    unsigned short* Wcat_w  = (unsigned short*)alloc((size_t)VV * 768 * 2);      // [1024][768]
    unsigned short* WT_mix  = (unsigned short*)alloc((size_t)3 * 65536 * 2);
    unsigned short* WT_tg   = (unsigned short*)alloc((size_t)65536 * 2);
    unsigned short* WT_al   = (unsigned short*)alloc((size_t)65536 * 2);
    unsigned short* xn      = (unsigned short*)alloc((size_t)MR * VV * 2);       // reused ph2
    unsigned short* qkv     = (unsigned short*)alloc((size_t)MR * 1536 * 2);
    unsigned short* vt_s    = (unsigned short*)alloc((size_t)BB * CC * TT * 2);
    unsigned short* vt_f    = (unsigned short*)alloc((size_t)BB * CC * TT * 2);
    unsigned short* rcat    = (unsigned short*)alloc((size_t)MR * 512 * 2);
    unsigned short* rfast   = (unsigned short*)alloc((size_t)MR * CC * 2);
    unsigned short* hhigh   = (unsigned short*)alloc((size_t)MR * CC * 2);
    // z and hcat overlay the (dead-by-then) qkv region
    unsigned short* z    = qkv;
    unsigned short* hcat = qkv + (size_t)MR * 768;

    // ---- weight prep ----
    prep_softmax_w<<<256, 256, 0, stream>>>(basis_low,  slow_q, 32,  WT_p1 + (size_t)0 * CC * VV);
    prep_softmax_w<<<256, 256, 0, stream>>>(basis_low,  slow_k, 32,  WT_p1 + (size_t)1 * CC * VV);
    prep_softmax_w<<<256, 256, 0, stream>>>(basis_low,  slow_v, 32,  WT_p1 + (size_t)2 * CC * VV);
    prep_softmax_w<<<256, 256, 0, stream>>>(basis_high, fast_q, 128, WT_p1 + (size_t)3 * CC * VV);
    prep_softmax_w<<<256, 256, 0, stream>>>(basis_high, fast_k, 128, WT_p1 + (size_t)4 * CC * VV);
    prep_softmax_w<<<256, 256, 0, stream>>>(basis_high, fast_v, 128, WT_p1 + (size_t)5 * CC * VV);
    prep_softmax_w<<<256, 256, 0, stream>>>(basis_low,  low_read,  32,  WT_read + (size_t)0 * CC * VV);
    prep_softmax_w<<<256, 256, 0, stream>>>(basis_mid,  mid_read,  64,  WT_read + (size_t)1 * CC * VV);
    prep_softmax_w<<<256, 256, 0, stream>>>(basis_high, high_read, 128, WT_read + (size_t)2 * CC * VV);
    prep_plain_w<<<1024, 256, 0, stream>>>(basis_low,  slow_o, 32,  slow_scale, mem_slow_scale, Wcat_o, 512, 0);
    prep_plain_w<<<1024, 256, 0, stream>>>(basis_high, fast_o, 128, fast_scale, mem_fast_scale, Wcat_o, 512, 256);
    prep_plain_w<<<1024, 256, 0, stream>>>(basis_low,  low_write,  32,  low_oscale,  op_low_scale,  Wcat_w, 768, 0);
    prep_plain_w<<<1024, 256, 0, stream>>>(basis_mid,  mid_write,  64,  mid_oscale,  op_mid_scale,  Wcat_w, 768, 256);
    prep_plain_w<<<1024, 256, 0, stream>>>(basis_high, high_write, 128, high_oscale, op_high_scale, Wcat_w, 768, 512);
    prep_T<<<256, 256, 0, stream>>>(tg_w, WT_tg);
    prep_T<<<256, 256, 0, stream>>>(alpha_w, WT_al);
    prep_T<<<256, 256, 0, stream>>>(low_mix,  WT_mix + 0 * 65536);
    prep_T<<<256, 256, 0, stream>>>(mid_mix,  WT_mix + 1 * 65536);
    prep_T<<<256, 256, 0, stream>>>(high_mix, WT_mix + 2 * 65536);

    // ---- phase 1 ----
    rmsnorm_k<<<MR, 256, 0, stream>>>(x, xn);
    { EpiP ep{}; ep.outb = qkv; ep.ldo = 1536; ep.coloff = 0;
      gemm_bt_k<0><<<dim3(24, 128), 256, 0, stream>>>(xn, 1024, WT_p1, 1024, ep); }
    transpose_TC<<<dim3(64, 8, 4), 256, 0, stream>>>(qkv + 512, 1536, vt_s);
    transpose_TC<<<dim3(64, 8, 4), 256, 0, stream>>>(qkv + 1280, 1536, vt_f);
    attn_k<<<512, 256, 0, stream>>>(qkv, 0,   256,  vt_s, slow_decay, rcat, 512, 768);
    attn_k<<<512, 256, 0, stream>>>(qkv, 768, 1024, vt_f, fast_decay, rfast, 256, 288);
    { EpiP ep{}; ep.outb = rcat; ep.ldo = 512; ep.coloff = 256;
      ep.bias = tg_b; ep.aux = rfast; ep.ldaux = 256;
      gemm_bt_k<1><<<dim3(4, 128), 256, 0, stream>>>(rcat, 512, WT_tg, 256, ep); }
    { EpiP ep{}; ep.outf = out; ep.addf = x; ep.ldo = 1024;
      gemm_bt_k<3><<<dim3(16, 128), 256, 0, stream>>>(rcat, 512, Wcat_o, 512, ep); }

    // ---- phase 2 ----
    rmsnorm_k<<<MR, 256, 0, stream>>>(out, xn);
    { EpiP ep{}; ep.outb = z; ep.ldo = 768; ep.coloff = 0;
      gemm_bt_k<0><<<dim3(12, 128), 256, 0, stream>>>(xn, 1024, WT_read, 1024, ep); }
    { EpiP ep{}; ep.outb = hcat; ep.ldo = 768; ep.coloff = 0; ep.bias = low_bias;
      gemm_bt_k<2><<<dim3(4, 128), 256, 0, stream>>>(z + 0, 768, WT_mix + 0 * 65536, 256, ep); }
    { EpiP ep{}; ep.outb = hcat; ep.ldo = 768; ep.coloff = 256; ep.bias = mid_bias;
      gemm_bt_k<2><<<dim3(4, 128), 256, 0, stream>>>(z + 256, 768, WT_mix + 1 * 65536, 256, ep); }
    { EpiP ep{}; ep.outb = hhigh; ep.ldo = 256; ep.coloff = 0; ep.bias = high_bias;
      gemm_bt_k<2><<<dim3(4, 128), 256, 0, stream>>>(z + 512, 768, WT_mix + 2 * 65536, 256, ep); }
    { EpiP ep{}; ep.outb = hcat; ep.ldo = 768; ep.coloff = 512;
      ep.bias = alpha_b; ep.aux = hhigh; ep.ldaux = 256;
      gemm_bt_k<1><<<dim3(4, 128), 256, 0, stream>>>(hcat, 768, WT_al, 256, ep); }
    { EpiP ep{}; ep.outf = out; ep.addf = out; ep.ldo = 1024;
      gemm_bt_k<3><<<dim3(16, 128), 256, 0, stream>>>(hcat, 768, Wcat_w, 768, ep); }
}

// Round 3
// 365.645 us; speedup vs baseline: 2.2364x; 1.7235x over previous
//
#include <hip/hip_runtime.h>
#include <math.h>

#define BB 4
#define TT 2048
#define VV 1024
#define CC 256
#define MR (BB*TT)   // 8192 rows

using short8  = __attribute__((ext_vector_type(8))) short;
using ushort8 = __attribute__((ext_vector_type(8))) unsigned short;
using f32x4   = __attribute__((ext_vector_type(4))) float;

__device__ __forceinline__ float bs2f(unsigned short s) {
    return __uint_as_float(((unsigned int)s) << 16);
}
__device__ __forceinline__ unsigned short f2bs(float f) {
    unsigned int u = __float_as_uint(f);
    u += 0x7fffu + ((u >> 16) & 1u);          // round-to-nearest-even
    return (unsigned short)(u >> 16);
}

// ---------------------------------------------------------------------------
// Fused multi-array fp32 -> bf16 cast (coalesced). grid = (njobs, 64)
struct CastJob { const float* src; unsigned short* dst; int n; };
struct CastArgs { CastJob j[17]; };

__global__ void cast_bf16_multi(CastArgs a) {
    CastJob jb = a.j[blockIdx.x];
    int off = (blockIdx.y * 256 + threadIdx.x) * 8;
    if (off + 8 > jb.n) return;
    float4 v0 = *reinterpret_cast<const float4*>(jb.src + off);
    float4 v1 = *reinterpret_cast<const float4*>(jb.src + off + 4);
    ushort8 u;
    u[0] = f2bs(v0.x); u[1] = f2bs(v0.y); u[2] = f2bs(v0.z); u[3] = f2bs(v0.w);
    u[4] = f2bs(v1.x); u[5] = f2bs(v1.y); u[6] = f2bs(v1.z); u[7] = f2bs(v1.w);
    *reinterpret_cast<ushort8*>(jb.dst + off) = u;
}

// Row softmax in place over [rows][1024] bf16. grid = rows, block = 256.
__global__ void softmax_rows(unsigned short* __restrict__ w) {
    int r = blockIdx.x, t = threadIdx.x;
    unsigned short* row = w + (size_t)r * 1024;
    ushort4 u = reinterpret_cast<ushort4*>(row)[t];
    float v0 = bs2f(u.x), v1 = bs2f(u.y), v2 = bs2f(u.z), v3 = bs2f(u.w);
    __shared__ float red[256];
    red[t] = fmaxf(fmaxf(v0, v1), fmaxf(v2, v3));
    __syncthreads();
    for (int o = 128; o > 0; o >>= 1) { if (t < o) red[t] = fmaxf(red[t], red[t + o]); __syncthreads(); }
    float mx = red[0]; __syncthreads();
    float e0 = expf(v0 - mx), e1 = expf(v1 - mx), e2 = expf(v2 - mx), e3 = expf(v3 - mx);
    red[t] = e0 + e1 + e2 + e3;
    __syncthreads();
    for (int o = 128; o > 0; o >>= 1) { if (t < o) red[t] += red[t + o]; __syncthreads(); }
    float inv = 1.f / red[0];
    ushort4 o4;
    o4.x = f2bs(e0 * inv); o4.y = f2bs(e1 * inv); o4.z = f2bs(e2 * inv); o4.w = f2bs(e3 * inv);
    reinterpret_cast<ushort4*>(row)[t] = o4;
}

// WT[n][k] = W[k][n], 256x256 fp32 -> bf16.  grid = 256, block = 256
__global__ void prep_T(const float* __restrict__ W, unsigned short* __restrict__ WT) {
    int n = blockIdx.x, k = threadIdx.x;
    WT[(size_t)n * 256 + k] = f2bs(W[(size_t)k * 256 + n]);
}

// ---------------------------------------------------------------------------
// RMS norm: one block per row (V=1024), bf16 out
__global__ void rmsnorm_k(const float* __restrict__ x, unsigned short* __restrict__ xn) {
    int row = blockIdx.x, t = threadIdx.x;
    const float4 v = reinterpret_cast<const float4*>(x + (size_t)row * VV)[t];
    __shared__ float red[256];
    red[t] = v.x * v.x + v.y * v.y + v.z * v.z + v.w * v.w;
    __syncthreads();
    for (int o = 128; o > 0; o >>= 1) { if (t < o) red[t] += red[t + o]; __syncthreads(); }
    float r = rsqrtf(red[0] * (1.f / VV) + 1.1920929e-7f);
    ushort4 u;
    u.x = f2bs(v.x * r); u.y = f2bs(v.y * r); u.z = f2bs(v.z * r); u.w = f2bs(v.w * r);
    reinterpret_cast<ushort4*>(xn + (size_t)row * VV)[t] = u;
}

// ---------------------------------------------------------------------------
// bf16 transpose per batch: (T,C) slice of qkv -> (C,T)
__global__ void transpose_TC(const unsigned short* __restrict__ src, int ldsrc,
                             unsigned short* __restrict__ dst) {
    __shared__ unsigned short tile[32][33];
    int b = blockIdx.z, t0 = blockIdx.x * 32, c0 = blockIdx.y * 32;
    int tx = threadIdx.x & 31, ty = threadIdx.x >> 5;
    #pragma unroll
    for (int i = 0; i < 4; ++i) {
        int r = ty + i * 8;
        tile[r][tx] = src[(size_t)(b * TT + t0 + r) * ldsrc + c0 + tx];
    }
    __syncthreads();
    #pragma unroll
    for (int i = 0; i < 4; ++i) {
        int r = ty + i * 8;
        dst[((size_t)b * CC + c0 + r) * TT + t0 + tx] = tile[tx][r];
    }
}

// ---------------------------------------------------------------------------
// GEMM: C[m,n] = sum_k A[m,k] * Bt[n,k]  (A,Bt bf16 row-major), 64x64 tile,
// 4 waves (2x2), mfma_f32_16x16x32_bf16. XOR-swizzled LDS (2-way = free).
struct EpiP {
    float* outf; const float* addf;
    unsigned short* outb; int ldo; int coloff;
    const float* bias;
    const unsigned short* aux; int ldaux;
    const float* s1; const float* s2;
};

template<int EPI>
__global__ __launch_bounds__(256)
void gemm_bt_k(const unsigned short* A, int lda,
               const unsigned short* Bt, int K, EpiP ep) {
    __shared__ short8 As[256], Bs[256];            // 64 rows x 4 chunks each
    const int tid = threadIdx.x;
    const int lane = tid & 63, wid = tid >> 6;
    const int wm = wid >> 1, wn = wid & 1;
    const int m0 = blockIdx.y * 64, n0 = blockIdx.x * 64;
    const int lrow = tid >> 2, lch = tid & 3;
    const int sws = lch ^ ((lrow >> 1) & 3);
    const unsigned short* ag = A + (size_t)(m0 + lrow) * lda + lch * 8;
    const unsigned short* bg = Bt + (size_t)(n0 + lrow) * K + lch * 8;

    f32x4 acc[2][2];
    #pragma unroll
    for (int i = 0; i < 2; ++i)
        #pragma unroll
        for (int j = 0; j < 2; ++j) acc[i][j] = {0.f, 0.f, 0.f, 0.f};

    const int g = lane >> 4;
    const int ra0 = wm * 32 + (lane & 15);
    const int rb0 = wn * 32 + (lane & 15);

    for (int k0 = 0; k0 < K; k0 += 32) {
        As[lrow * 4 + sws] = *reinterpret_cast<const short8*>(ag + k0);
        Bs[lrow * 4 + sws] = *reinterpret_cast<const short8*>(bg + k0);
        __syncthreads();
        short8 af[2], bf[2];
        #pragma unroll
        for (int i = 0; i < 2; ++i) {
            int ra = ra0 + i * 16;
            af[i] = As[ra * 4 + (g ^ ((ra >> 1) & 3))];
            int rb = rb0 + i * 16;
            bf[i] = Bs[rb * 4 + (g ^ ((rb >> 1) & 3))];
        }
        #pragma unroll
        for (int i = 0; i < 2; ++i)
            #pragma unroll
            for (int j = 0; j < 2; ++j)
                acc[i][j] = __builtin_amdgcn_mfma_f32_16x16x32_bf16(af[i], bf[j], acc[i][j], 0, 0, 0);
        __syncthreads();
    }

    #pragma unroll
    for (int i = 0; i < 2; ++i) {
        #pragma unroll
        for (int j = 0; j < 2; ++j) {
            #pragma unroll
            for (int r = 0; r < 4; ++r) {
                int m = m0 + wm * 32 + i * 16 + (lane >> 4) * 4 + r;
                int n = n0 + wn * 32 + j * 16 + (lane & 15);
                float v = acc[i][j][r];
                if constexpr (EPI == 0) {                       // plain bf16 store
                    ep.outb[(size_t)m * ep.ldo + ep.coloff + n] = f2bs(v);
                } else if constexpr (EPI == 1) {                // sigmoid(acc+bias)*aux
                    float s = 1.f / (1.f + expf(-(v + ep.bias[n])));
                    float a = bs2f(ep.aux[(size_t)m * ep.ldaux + n]);
                    ep.outb[(size_t)m * ep.ldo + ep.coloff + n] = f2bs(s * a);
                } else if constexpr (EPI == 2) {                // exact gelu(acc+bias)
                    float z = v + ep.bias[n];
                    float h = 0.5f * z * (1.f + erff(z * 0.70710678118654752f));
                    ep.outb[(size_t)m * ep.ldo + ep.coloff + n] = f2bs(h);
                } else if constexpr (EPI == 3) {                // outf = addf + acc
                    size_t idx = (size_t)m * ep.ldo + n;
                    ep.outf[idx] = ep.addf[idx] + v;
                } else {                                        // scaled bf16 store
                    ep.outb[(size_t)m * ep.ldo + ep.coloff + n] = f2bs(v * ep.s1[0] * ep.s2[0]);
                }
            }
        }
    }
}

// ---------------------------------------------------------------------------
// Decay-weighted retrieval, 4 waves/block splitting the s-scan.
__global__ __launch_bounds__(256)
void attn_k(const unsigned short* __restrict__ qkv, int qoff, int koff,
            const unsigned short* __restrict__ vt,
            const float* __restrict__ dlogit,
            unsigned short* __restrict__ rout, int ldr, int win) {
    int blk = blockIdx.x;
    int b = blk >> 7;               // 128 t-tiles per batch
    int t0 = (blk & 127) << 4;
    int tid = threadIdx.x;
    int lane = tid & 63, wid = tid >> 6;
    float dec = 1.f / (1.f + expf(-dlogit[0]));
    float l2d = log2f(dec);

    __shared__ short8 Pl[4][64];    // per-wave 16x32 bf16, swizzled chunks
    __shared__ float  red[16][260]; // LD=260 -> exactly 2-way bank alias (free)

    short8 qf[8];
    const size_t rowq = (size_t)(b * TT + t0 + (lane & 15)) * 1536 + qoff + (lane >> 4) * 8;
    #pragma unroll
    for (int ch = 0; ch < 8; ++ch)
        qf[ch] = *reinterpret_cast<const short8*>(qkv + rowq + ch * 32);

    f32x4 racc[16];
    #pragma unroll
    for (int i = 0; i < 16; ++i) racc[i] = {0.f, 0.f, 0.f, 0.f};

    unsigned short* pb = reinterpret_cast<unsigned short*>(&Pl[wid][0]);

    int sBeg = t0 & ~31;
    int sEnd = TT;
    if (win > 0) { int e = (t0 + 16 + win + 31) & ~31; sEnd = e < TT ? e : TT; }
    const int tl = (lane >> 4) * 4;

    for (int s0 = sBeg + wid * 32; s0 < sEnd; s0 += 128) {
        #pragma unroll
        for (int h = 0; h < 2; ++h) {
            f32x4 sacc = {0.f, 0.f, 0.f, 0.f};
            const unsigned short* kb =
                qkv + (size_t)(b * TT + s0 + h * 16 + (lane & 15)) * 1536 + koff + (lane >> 4) * 8;
            #pragma unroll
            for (int ch = 0; ch < 8; ++ch) {
                short8 kf = *reinterpret_cast<const short8*>(kb + ch * 32);
                sacc = __builtin_amdgcn_mfma_f32_16x16x32_bf16(qf[ch], kf, sacc, 0, 0, 0);
            }
            int scol = s0 + h * 16 + (lane & 15);
            #pragma unroll
            for (int r = 0; r < 4; ++r) {
                int trow = t0 + tl + r;
                int d = scol - trow;
                float w = (d > 0) ? exp2f(l2d * (float)(d - 1)) : 0.f;
                int prow = tl + r, pcol = h * 16 + (lane & 15);
                int sw = (pcol >> 3) ^ ((prow >> 1) & 3);
                pb[(prow * 4 + sw) * 8 + (pcol & 7)] = f2bs(sacc[r] * w);
            }
        }
        asm volatile("s_waitcnt lgkmcnt(0)" ::: "memory");
        __builtin_amdgcn_sched_barrier(0);
        short8 pf;
        { int prow = lane & 15; pf = Pl[wid][prow * 4 + ((lane >> 4) ^ ((prow >> 1) & 3))]; }
        const unsigned short* vb = vt + ((size_t)b * CC + (lane & 15)) * TT + s0 + (lane >> 4) * 8;
        #pragma unroll
        for (int nt = 0; nt < 16; ++nt) {
            short8 vf = *reinterpret_cast<const short8*>(vb + (size_t)nt * 16 * TT);
            racc[nt] = __builtin_amdgcn_mfma_f32_16x16x32_bf16(pf, vf, racc[nt], 0, 0, 0);
        }
    }

    // cross-wave reduction into red[][]
    for (int w = 0; w < 4; ++w) {
        if (wid == w) {
            #pragma unroll
            for (int nt = 0; nt < 16; ++nt)
                #pragma unroll
                for (int r = 0; r < 4; ++r) {
                    int row = tl + r, col = nt * 16 + (lane & 15);
                    if (w == 0) red[row][col] = racc[nt][r];
                    else        red[row][col] += racc[nt][r];
                }
        }
        __syncthreads();
    }

    // cooperative write-out: thread -> (row = tid>>4, 16 cols)
    {
        int row = tid >> 4, c0 = (tid & 15) * 16;
        ushort8 lo, hi;
        #pragma unroll
        for (int j = 0; j < 8; ++j) lo[j] = f2bs(red[row][c0 + j]);
        #pragma unroll
        for (int j = 0; j < 8; ++j) hi[j] = f2bs(red[row][c0 + 8 + j]);
        unsigned short* dst = rout + (size_t)(b * TT + t0 + row) * ldr + c0;
        *reinterpret_cast<ushort8*>(dst)     = lo;
        *reinterpret_cast<ushort8*>(dst + 8) = hi;
    }
}

// ---------------------------------------------------------------------------
extern "C" void kernel_launch(void* const* d_in, const int* in_sizes, int n_in,
                              void* d_out, int out_size, void* d_ws, size_t ws_size,
                              hipStream_t stream) {
    (void)in_sizes; (void)n_in; (void)out_size; (void)ws_size;
    const float* x          = (const float*)d_in[0];
    const float* basis_low  = (const float*)d_in[1];
    const float* basis_mid  = (const float*)d_in[2];
    const float* basis_high = (const float*)d_in[3];
    const float* slow_q = (const float*)d_in[4];
    const float* slow_k = (const float*)d_in[5];
    const float* slow_v = (const float*)d_in[6];
    const float* slow_o = (const float*)d_in[7];
    const float* slow_decay = (const float*)d_in[8];
    const float* slow_scale = (const float*)d_in[9];
    const float* fast_q = (const float*)d_in[10];
    const float* fast_k = (const float*)d_in[11];
    const float* fast_v = (const float*)d_in[12];
    const float* fast_o = (const float*)d_in[13];
    const float* fast_decay = (const float*)d_in[14];
    const float* fast_scale = (const float*)d_in[15];
    const float* low_read  = (const float*)d_in[16];
    const float* low_write = (const float*)d_in[17];
    const float* low_mix   = (const float*)d_in[18];
    const float* low_bias  = (const float*)d_in[19];
    const float* low_oscale= (const float*)d_in[20];
    const float* mid_read  = (const float*)d_in[21];
    const float* mid_write = (const float*)d_in[22];
    const float* mid_mix   = (const float*)d_in[23];
    const float* mid_bias  = (const float*)d_in[24];
    const float* mid_oscale= (const float*)d_in[25];
    const float* high_read  = (const float*)d_in[26];
    const float* high_write = (const float*)d_in[27];
    const float* high_mix   = (const float*)d_in[28];
    const float* high_bias  = (const float*)d_in[29];
    const float* high_oscale= (const float*)d_in[30];
    const float* tg_w    = (const float*)d_in[31];
    const float* tg_b    = (const float*)d_in[32];
    const float* alpha_w = (const float*)d_in[33];
    const float* alpha_b = (const float*)d_in[34];
    const float* mem_slow_scale = (const float*)d_in[35];
    const float* mem_fast_scale = (const float*)d_in[36];
    const float* op_low_scale   = (const float*)d_in[37];
    const float* op_mid_scale   = (const float*)d_in[38];
    const float* op_high_scale  = (const float*)d_in[39];
    float* out = (float*)d_out;

    char* ws = (char*)d_ws;
    size_t off = 0;
    auto alloc = [&](size_t n) { char* p = ws + off; off += (n + 255) & ~(size_t)255; return p; };
    // WT_p1 and WT_read MUST be adjacent (single softmax launch over 2304 rows)
    unsigned short* WT_p1   = (unsigned short*)alloc((size_t)6 * CC * VV * 2);   // [1536][1024]
    unsigned short* WT_read = (unsigned short*)alloc((size_t)3 * CC * VV * 2);   // [768][1024]
    unsigned short* Wcat_o  = (unsigned short*)alloc((size_t)VV * 512 * 2);      // [1024][512]
    unsigned short* Wcat_w  = (unsigned short*)alloc((size_t)VV * 768 * 2);      // [1024][768]
    unsigned short* WT_mix  = (unsigned short*)alloc((size_t)3 * 65536 * 2);
    unsigned short* WT_tg   = (unsigned short*)alloc((size_t)65536 * 2);
    unsigned short* WT_al   = (unsigned short*)alloc((size_t)65536 * 2);
    // bf16 casts of basis / coef arrays
    unsigned short* bb_low  = (unsigned short*)alloc((size_t)VV * 32 * 2);
    unsigned short* bb_mid  = (unsigned short*)alloc((size_t)VV * 64 * 2);
    unsigned short* bb_high = (unsigned short*)alloc((size_t)VV * 128 * 2);
    unsigned short* cqkv_l  = (unsigned short*)alloc((size_t)768 * 32 * 2);      // slow q,k,v
    unsigned short* cqkv_h  = (unsigned short*)alloc((size_t)768 * 128 * 2);     // fast q,k,v
    unsigned short* crd_l   = (unsigned short*)alloc((size_t)256 * 32 * 2);
    unsigned short* crd_m   = (unsigned short*)alloc((size_t)256 * 64 * 2);
    unsigned short* crd_h   = (unsigned short*)alloc((size_t)256 * 128 * 2);
    unsigned short* cO_s    = (unsigned short*)alloc((size_t)256 * 32 * 2);
    unsigned short* cO_f    = (unsigned short*)alloc((size_t)256 * 128 * 2);
    unsigned short* cW_l    = (unsigned short*)alloc((size_t)256 * 32 * 2);
    unsigned short* cW_m    = (unsigned short*)alloc((size_t)256 * 64 * 2);
    unsigned short* cW_h    = (unsigned short*)alloc((size_t)256 * 128 * 2);
    unsigned short* xn      = (unsigned short*)alloc((size_t)MR * VV * 2);       // reused ph2
    unsigned short* qkv     = (unsigned short*)alloc((size_t)MR * 1536 * 2);
    unsigned short* vt_s    = (unsigned short*)alloc((size_t)BB * CC * TT * 2);
    unsigned short* vt_f    = (unsigned short*)alloc((size_t)BB * CC * TT * 2);
    unsigned short* rcat    = (unsigned short*)alloc((size_t)MR * 512 * 2);
    unsigned short* rfast   = (unsigned short*)alloc((size_t)MR * CC * 2);
    unsigned short* hhigh   = (unsigned short*)alloc((size_t)MR * CC * 2);
    // z and hcat overlay the (dead-by-then) qkv region
    unsigned short* z    = qkv;
    unsigned short* hcat = qkv + (size_t)MR * 768;

    // ---- weight prep: casts ----
    {
        CastArgs ca;
        int i = 0;
        auto J = [&](const float* s, unsigned short* d, int n) { ca.j[i].src = s; ca.j[i].dst = d; ca.j[i].n = n; ++i; };
        J(basis_low,  bb_low,  VV * 32);
        J(basis_mid,  bb_mid,  VV * 64);
        J(basis_high, bb_high, VV * 128);
        J(slow_q, cqkv_l + 0 * 256 * 32, 256 * 32);
        J(slow_k, cqkv_l + 1 * 256 * 32, 256 * 32);
        J(slow_v, cqkv_l + 2 * 256 * 32, 256 * 32);
        J(fast_q, cqkv_h + 0 * 256 * 128, 256 * 128);
        J(fast_k, cqkv_h + 1 * 256 * 128, 256 * 128);
        J(fast_v, cqkv_h + 2 * 256 * 128, 256 * 128);
        J(low_read,  crd_l, 256 * 32);
        J(mid_read,  crd_m, 256 * 64);
        J(high_read, crd_h, 256 * 128);
        J(slow_o,    cO_s,  256 * 32);
        J(fast_o,    cO_f,  256 * 128);
        J(low_write, cW_l,  256 * 32);
        J(mid_write, cW_m,  256 * 64);
        J(high_write,cW_h,  256 * 128);
        cast_bf16_multi<<<dim3(17, 64), 256, 0, stream>>>(ca);
    }

    // ---- softmax-weight logits via MFMA gemm (WT layout), then row softmax --
    { EpiP ep{}; ep.outb = WT_p1; ep.ldo = VV; ep.coloff = 0;
      gemm_bt_k<0><<<dim3(16, 12), 256, 0, stream>>>(cqkv_l, 32, bb_low, 32, ep); }
    { EpiP ep{}; ep.outb = WT_p1 + (size_t)768 * VV; ep.ldo = VV; ep.coloff = 0;
      gemm_bt_k<0><<<dim3(16, 12), 256, 0, stream>>>(cqkv_h, 128, bb_high, 128, ep); }
    { EpiP ep{}; ep.outb = WT_read; ep.ldo = VV; ep.coloff = 0;
      gemm_bt_k<0><<<dim3(16, 4), 256, 0, stream>>>(crd_l, 32, bb_low, 32, ep); }
    { EpiP ep{}; ep.outb = WT_read + (size_t)256 * VV; ep.ldo = VV; ep.coloff = 0;
      gemm_bt_k<0><<<dim3(16, 4), 256, 0, stream>>>(crd_m, 64, bb_mid, 64, ep); }
    { EpiP ep{}; ep.outb = WT_read + (size_t)512 * VV; ep.ldo = VV; ep.coloff = 0;
      gemm_bt_k<0><<<dim3(16, 4), 256, 0, stream>>>(crd_h, 128, bb_high, 128, ep); }
    softmax_rows<<<2304, 256, 0, stream>>>(WT_p1);   // WT_p1 (1536) + WT_read (768), adjacent

    // ---- plain (projection) weights via MFMA gemm, scale epilogue ----
    { EpiP ep{}; ep.outb = Wcat_o; ep.ldo = 512; ep.coloff = 0;   ep.s1 = slow_scale; ep.s2 = mem_slow_scale;
      gemm_bt_k<4><<<dim3(4, 16), 256, 0, stream>>>(bb_low, 32, cO_s, 32, ep); }
    { EpiP ep{}; ep.outb = Wcat_o; ep.ldo = 512; ep.coloff = 256; ep.s1 = fast_scale; ep.s2 = mem_fast_scale;
      gemm_bt_k<4><<<dim3(4, 16), 256, 0, stream>>>(bb_high, 128, cO_f, 128, ep); }
    { EpiP ep{}; ep.outb = Wcat_w; ep.ldo = 768; ep.coloff = 0;   ep.s1 = low_oscale;  ep.s2 = op_low_scale;
      gemm_bt_k<4><<<dim3(4, 16), 256, 0, stream>>>(bb_low, 32, cW_l, 32, ep); }
    { EpiP ep{}; ep.outb = Wcat_w; ep.ldo = 768; ep.coloff = 256; ep.s1 = mid_oscale;  ep.s2 = op_mid_scale;
      gemm_bt_k<4><<<dim3(4, 16), 256, 0, stream>>>(bb_mid, 64, cW_m, 64, ep); }
    { EpiP ep{}; ep.outb = Wcat_w; ep.ldo = 768; ep.coloff = 512; ep.s1 = high_oscale; ep.s2 = op_high_scale;
      gemm_bt_k<4><<<dim3(4, 16), 256, 0, stream>>>(bb_high, 128, cW_h, 128, ep); }

    // ---- small C x C transposes ----
    prep_T<<<256, 256, 0, stream>>>(tg_w, WT_tg);
    prep_T<<<256, 256, 0, stream>>>(alpha_w, WT_al);
    prep_T<<<256, 256, 0, stream>>>(low_mix,  WT_mix + 0 * 65536);
    prep_T<<<256, 256, 0, stream>>>(mid_mix,  WT_mix + 1 * 65536);
    prep_T<<<256, 256, 0, stream>>>(high_mix, WT_mix + 2 * 65536);

    // ---- phase 1 ----
    rmsnorm_k<<<MR, 256, 0, stream>>>(x, xn);
    { EpiP ep{}; ep.outb = qkv; ep.ldo = 1536; ep.coloff = 0;
      gemm_bt_k<0><<<dim3(24, 128), 256, 0, stream>>>(xn, 1024, WT_p1, 1024, ep); }
    transpose_TC<<<dim3(64, 8, 4), 256, 0, stream>>>(qkv + 512, 1536, vt_s);
    transpose_TC<<<dim3(64, 8, 4), 256, 0, stream>>>(qkv + 1280, 1536, vt_f);
    attn_k<<<512, 256, 0, stream>>>(qkv, 0,   256,  vt_s, slow_decay, rcat, 512, 768);
    attn_k<<<512, 256, 0, stream>>>(qkv, 768, 1024, vt_f, fast_decay, rfast, 256, 288);
    { EpiP ep{}; ep.outb = rcat; ep.ldo = 512; ep.coloff = 256;
      ep.bias = tg_b; ep.aux = rfast; ep.ldaux = 256;
      gemm_bt_k<1><<<dim3(4, 128), 256, 0, stream>>>(rcat, 512, WT_tg, 256, ep); }
    { EpiP ep{}; ep.outf = out; ep.addf = x; ep.ldo = 1024;
      gemm_bt_k<3><<<dim3(16, 128), 256, 0, stream>>>(rcat, 512, Wcat_o, 512, ep); }

    // ---- phase 2 ----
    rmsnorm_k<<<MR, 256, 0, stream>>>(out, xn);
    { EpiP ep{}; ep.outb = z; ep.ldo = 768; ep.coloff = 0;
      gemm_bt_k<0><<<dim3(12, 128), 256, 0, stream>>>(xn, 1024, WT_read, 1024, ep); }
    { EpiP ep{}; ep.outb = hcat; ep.ldo = 768; ep.coloff = 0; ep.bias = low_bias;
      gemm_bt_k<2><<<dim3(4, 128), 256, 0, stream>>>(z + 0, 768, WT_mix + 0 * 65536, 256, ep); }
    { EpiP ep{}; ep.outb = hcat; ep.ldo = 768; ep.coloff = 256; ep.bias = mid_bias;
      gemm_bt_k<2><<<dim3(4, 128), 256, 0, stream>>>(z + 256, 768, WT_mix + 1 * 65536, 256, ep); }
    { EpiP ep{}; ep.outb = hhigh; ep.ldo = 256; ep.coloff = 0; ep.bias = high_bias;
      gemm_bt_k<2><<<dim3(4, 128), 256, 0, stream>>>(z + 512, 768, WT_mix + 2 * 65536, 256, ep); }
    { EpiP ep{}; ep.outb = hcat; ep.ldo = 768; ep.coloff = 512;
      ep.bias = alpha_b; ep.aux = hhigh; ep.ldaux = 256;
      gemm_bt_k<1><<<dim3(4, 128), 256, 0, stream>>>(hcat, 768, WT_al, 256, ep); }
    { EpiP ep{}; ep.outf = out; ep.addf = out; ep.ldo = 1024;
      gemm_bt_k<3><<<dim3(16, 128), 256, 0, stream>>>(hcat, 768, Wcat_w, 768, ep); }
}